// Round 1
// baseline (2352.024 us; speedup 1.0000x reference)
//
#include <hip/hip_runtime.h>
#include <math.h>

// Problem constants
#define Bn  4
#define Sn  2048
#define Hn  768
#define NHn 12
#define DHn 64
#define WHn 128
#define MR  (Bn * Sn)      // 8192 rows
#define EPSf 1e-12f

// ---------------------------------------------------------------------------
// Generic tiled fp32 GEMM: C[M,N] = A[M,K] @ W[K,N] + bias[N]
// 64x64 tile, 256 threads, 4x4 micro-tile per thread, K-step 16.
// LDS stored k-major (transposed) so the inner loop is 2x ds_read_b128.
// ---------------------------------------------------------------------------
__global__ __launch_bounds__(256) void proj_gemm(const float* __restrict__ A,
                                                 const float* __restrict__ W,
                                                 const float* __restrict__ bias,
                                                 float* __restrict__ C,
                                                 int M, int N, int K) {
    __shared__ float At[16][68];   // [k][row]
    __shared__ float Bs[16][68];   // [k][col]
    const int tid = threadIdx.x;
    const int tx = tid & 15, ty = tid >> 4;
    const int row0 = blockIdx.y << 6, col0 = blockIdx.x << 6;
    float acc[4][4] = {};

    for (int k0 = 0; k0 < K; k0 += 16) {
        {
            const int r = tid >> 2;            // 0..63
            const int c = (tid & 3) << 2;      // 0,4,8,12
            float4 av = *(const float4*)(A + (size_t)(row0 + r) * K + (k0 + c));
            At[c + 0][r] = av.x; At[c + 1][r] = av.y;
            At[c + 2][r] = av.z; At[c + 3][r] = av.w;
            const int wr = tid >> 4;           // 0..15
            const int wc = (tid & 15) << 2;    // 0..60
            *(float4*)&Bs[wr][wc] =
                *(const float4*)(W + (size_t)(k0 + wr) * N + (col0 + wc));
        }
        __syncthreads();
#pragma unroll
        for (int kk = 0; kk < 16; ++kk) {
            float4 a4 = *(const float4*)&At[kk][ty << 2];
            float4 b4 = *(const float4*)&Bs[kk][tx << 2];
            const float a[4] = {a4.x, a4.y, a4.z, a4.w};
            const float b[4] = {b4.x, b4.y, b4.z, b4.w};
#pragma unroll
            for (int i = 0; i < 4; ++i)
#pragma unroll
                for (int j = 0; j < 4; ++j) acc[i][j] += a[i] * b[j];
        }
        __syncthreads();
    }
#pragma unroll
    for (int i = 0; i < 4; ++i) {
        const int r = row0 + (ty << 2) + i;
        const int c = col0 + (tx << 2);
        float4 o;
        o.x = acc[i][0] + bias[c + 0];
        o.y = acc[i][1] + bias[c + 1];
        o.z = acc[i][2] + bias[c + 2];
        o.w = acc[i][3] + bias[c + 3];
        *(float4*)(C + (size_t)r * N + c) = o;
    }
}

// ---------------------------------------------------------------------------
// Gate head: per row of g[8192,128]: LayerNorm -> relu -> @Wg2[128,12]+bg2
// -> sigmoid -> gates[8192,12]
// ---------------------------------------------------------------------------
__global__ __launch_bounds__(128) void gate_kernel(const float* __restrict__ g,
                                                   const float* __restrict__ lw,
                                                   const float* __restrict__ lb,
                                                   const float* __restrict__ Wg2,
                                                   const float* __restrict__ bg2,
                                                   float* __restrict__ gates) {
    const int row = blockIdx.x;    // 0..8191
    const int t = threadIdx.x;     // 0..127
    __shared__ float red[128];
    __shared__ float ys[128];
    const float x = g[(size_t)row * WHn + t];
    red[t] = x; __syncthreads();
    for (int s2 = 64; s2 > 0; s2 >>= 1) {
        if (t < s2) red[t] += red[t + s2];
        __syncthreads();
    }
    const float mu = red[0] * (1.0f / WHn);
    __syncthreads();
    const float d = x - mu;
    red[t] = d * d; __syncthreads();
    for (int s2 = 64; s2 > 0; s2 >>= 1) {
        if (t < s2) red[t] += red[t + s2];
        __syncthreads();
    }
    const float var = red[0] * (1.0f / WHn);
    float y = d * rsqrtf(var + EPSf) * lw[t] + lb[t];
    y = fmaxf(y, 0.0f);
    ys[t] = y; __syncthreads();
    if (t < NHn) {
        float acc = bg2[t];
        for (int w = 0; w < WHn; ++w) acc += ys[w] * Wg2[w * NHn + t];
        gates[(size_t)row * NHn + t] = 1.0f / (1.0f + __expf(-acc));
    }
}

// ---------------------------------------------------------------------------
// scores = (Q @ K^T) * (1/8) * gate[b,q,h] + mask[b,c]   (pre-softmax)
// 64x64 output tile per block, full K=64 staged transposed in LDS.
// ---------------------------------------------------------------------------
__global__ __launch_bounds__(256) void scores_kernel(const float* __restrict__ qb,
                                                     const float* __restrict__ kb,
                                                     const float* __restrict__ gates,
                                                     const float* __restrict__ amask,
                                                     float* __restrict__ probs) {
    __shared__ float Qt[64][68];   // [d][qrow]
    __shared__ float Kt[64][68];   // [d][kcol]
    const int tid = threadIdx.x;
    const int tx = tid & 15, ty = tid >> 4;
    const int bh = blockIdx.z;
    const int b = bh / NHn, h = bh - b * NHn;
    const int q0 = blockIdx.y << 6, c0 = blockIdx.x << 6;
    const float* Q  = qb + (size_t)b * Sn * Hn + (size_t)h * DHn;
    const float* Kp = kb + (size_t)b * Sn * Hn + (size_t)h * DHn;

#pragma unroll
    for (int t2 = 0; t2 < 4; ++t2) {
        const int f = tid + (t2 << 8);   // 0..1023
        const int r = f >> 4;            // 0..63
        const int c = (f & 15) << 2;     // 0..60
        float4 qv = *(const float4*)(Q + (size_t)(q0 + r) * Hn + c);
        Qt[c + 0][r] = qv.x; Qt[c + 1][r] = qv.y;
        Qt[c + 2][r] = qv.z; Qt[c + 3][r] = qv.w;
        float4 kv = *(const float4*)(Kp + (size_t)(c0 + r) * Hn + c);
        Kt[c + 0][r] = kv.x; Kt[c + 1][r] = kv.y;
        Kt[c + 2][r] = kv.z; Kt[c + 3][r] = kv.w;
    }
    __syncthreads();

    float acc[4][4] = {};
#pragma unroll 8
    for (int d = 0; d < 64; ++d) {
        float4 a4 = *(const float4*)&Qt[d][ty << 2];
        float4 b4 = *(const float4*)&Kt[d][tx << 2];
        const float a[4] = {a4.x, a4.y, a4.z, a4.w};
        const float b[4] = {b4.x, b4.y, b4.z, b4.w};
#pragma unroll
        for (int i = 0; i < 4; ++i)
#pragma unroll
            for (int j = 0; j < 4; ++j) acc[i][j] += a[i] * b[j];
    }

    const int cc = c0 + (tx << 2);
    float m[4];
#pragma unroll
    for (int j = 0; j < 4; ++j)
        m[j] = (1.0f - amask[(size_t)b * Sn + cc + j]) * -10000.0f;
#pragma unroll
    for (int i = 0; i < 4; ++i) {
        const int qr = q0 + (ty << 2) + i;
        const float gt = gates[((size_t)b * Sn + qr) * NHn + h] * 0.125f;
        float4 o;
        o.x = acc[i][0] * gt + m[0];
        o.y = acc[i][1] * gt + m[1];
        o.z = acc[i][2] * gt + m[2];
        o.w = acc[i][3] * gt + m[3];
        *(float4*)(probs + (size_t)bh * Sn * Sn + (size_t)qr * Sn + cc) = o;
    }
}

// ---------------------------------------------------------------------------
// In-place row softmax over last dim (2048) of probs.
// ---------------------------------------------------------------------------
__global__ __launch_bounds__(256) void softmax_kernel(float* __restrict__ probs) {
    const size_t row = blockIdx.x;
    float* p = probs + row * (size_t)Sn;
    const int t = threadIdx.x;
    float4 x0 = *(float4*)(p + (t << 2));
    float4 x1 = *(float4*)(p + 1024 + (t << 2));
    float m = fmaxf(fmaxf(fmaxf(x0.x, x0.y), fmaxf(x0.z, x0.w)),
                    fmaxf(fmaxf(x1.x, x1.y), fmaxf(x1.z, x1.w)));
    __shared__ float red[256];
    red[t] = m; __syncthreads();
    for (int s2 = 128; s2 > 0; s2 >>= 1) {
        if (t < s2) red[t] = fmaxf(red[t], red[t + s2]);
        __syncthreads();
    }
    m = red[0]; __syncthreads();
    x0.x = __expf(x0.x - m); x0.y = __expf(x0.y - m);
    x0.z = __expf(x0.z - m); x0.w = __expf(x0.w - m);
    x1.x = __expf(x1.x - m); x1.y = __expf(x1.y - m);
    x1.z = __expf(x1.z - m); x1.w = __expf(x1.w - m);
    red[t] = x0.x + x0.y + x0.z + x0.w + x1.x + x1.y + x1.z + x1.w;
    __syncthreads();
    for (int s2 = 128; s2 > 0; s2 >>= 1) {
        if (t < s2) red[t] += red[t + s2];
        __syncthreads();
    }
    const float inv = 1.0f / red[0];
    x0.x *= inv; x0.y *= inv; x0.z *= inv; x0.w *= inv;
    x1.x *= inv; x1.y *= inv; x1.z *= inv; x1.w *= inv;
    *(float4*)(p + (t << 2)) = x0;
    *(float4*)(p + 1024 + (t << 2)) = x1;
}

// ---------------------------------------------------------------------------
// ctx[b,q,h*64+d] = probs[bh] @ V_h   (M=2048, K=2048, N=64 per bh)
// ---------------------------------------------------------------------------
__global__ __launch_bounds__(256) void pv_gemm(const float* __restrict__ probs,
                                               const float* __restrict__ vb,
                                               float* __restrict__ ctx) {
    __shared__ float Pt[16][68];
    __shared__ float Vs[16][68];
    const int tid = threadIdx.x;
    const int tx = tid & 15, ty = tid >> 4;
    const int bh = blockIdx.z;
    const int b = bh / NHn, h = bh - b * NHn;
    const int q0 = blockIdx.y << 6;
    const float* P = probs + (size_t)bh * Sn * Sn;
    const float* V = vb + (size_t)b * Sn * Hn + (size_t)h * DHn;
    float acc[4][4] = {};

    for (int k0 = 0; k0 < Sn; k0 += 16) {
        {
            const int r = tid >> 2;
            const int c = (tid & 3) << 2;
            float4 pv = *(const float4*)(P + (size_t)(q0 + r) * Sn + (k0 + c));
            Pt[c + 0][r] = pv.x; Pt[c + 1][r] = pv.y;
            Pt[c + 2][r] = pv.z; Pt[c + 3][r] = pv.w;
            const int wr = tid >> 4;
            const int wc = (tid & 15) << 2;
            *(float4*)&Vs[wr][wc] =
                *(const float4*)(V + (size_t)(k0 + wr) * Hn + wc);
        }
        __syncthreads();
#pragma unroll
        for (int kk = 0; kk < 16; ++kk) {
            float4 a4 = *(const float4*)&Pt[kk][ty << 2];
            float4 b4 = *(const float4*)&Vs[kk][tx << 2];
            const float a[4] = {a4.x, a4.y, a4.z, a4.w};
            const float b[4] = {b4.x, b4.y, b4.z, b4.w};
#pragma unroll
            for (int i = 0; i < 4; ++i)
#pragma unroll
                for (int j = 0; j < 4; ++j) acc[i][j] += a[i] * b[j];
        }
        __syncthreads();
    }
#pragma unroll
    for (int i = 0; i < 4; ++i) {
        const int qr = q0 + (ty << 2) + i;
        float4 o;
        o.x = acc[i][0]; o.y = acc[i][1]; o.z = acc[i][2]; o.w = acc[i][3];
        *(float4*)(ctx + ((size_t)b * Sn + qr) * Hn + h * DHn + (tx << 2)) = o;
    }
}

// ---------------------------------------------------------------------------
// out = LayerNorm(ctxo + hidden) * lw + lb   (row length 768 = 3*256)
// ---------------------------------------------------------------------------
__global__ __launch_bounds__(256) void final_ln(const float* __restrict__ xo,
                                                const float* __restrict__ hs,
                                                const float* __restrict__ lw,
                                                const float* __restrict__ lb,
                                                float* __restrict__ out) {
    const int row = blockIdx.x;
    const int t = threadIdx.x;
    const float* a = xo + (size_t)row * Hn;
    const float* r = hs + (size_t)row * Hn;
    const float x0 = a[t] + r[t];
    const float x1 = a[t + 256] + r[t + 256];
    const float x2 = a[t + 512] + r[t + 512];
    __shared__ float red[256];
    red[t] = x0 + x1 + x2; __syncthreads();
    for (int s2 = 128; s2 > 0; s2 >>= 1) {
        if (t < s2) red[t] += red[t + s2];
        __syncthreads();
    }
    const float mu = red[0] * (1.0f / Hn);
    __syncthreads();
    const float d0 = x0 - mu, d1 = x1 - mu, d2 = x2 - mu;
    red[t] = d0 * d0 + d1 * d1 + d2 * d2; __syncthreads();
    for (int s2 = 128; s2 > 0; s2 >>= 1) {
        if (t < s2) red[t] += red[t + s2];
        __syncthreads();
    }
    const float rs = rsqrtf(red[0] * (1.0f / Hn) + EPSf);
    out[(size_t)row * Hn + t]       = d0 * rs * lw[t]       + lb[t];
    out[(size_t)row * Hn + t + 256] = d1 * rs * lw[t + 256] + lb[t + 256];
    out[(size_t)row * Hn + t + 512] = d2 * rs * lw[t + 512] + lb[t + 512];
}

// ---------------------------------------------------------------------------
extern "C" void kernel_launch(void* const* d_in, const int* in_sizes, int n_in,
                              void* d_out, int out_size, void* d_ws, size_t ws_size,
                              hipStream_t stream) {
    const float* hidden = (const float*)d_in[0];
    const float* amask  = (const float*)d_in[1];
    const float* Wq = (const float*)d_in[2];  const float* bq = (const float*)d_in[3];
    const float* Wk = (const float*)d_in[4];  const float* bk = (const float*)d_in[5];
    const float* Wv = (const float*)d_in[6];  const float* bv = (const float*)d_in[7];
    const float* Wg1 = (const float*)d_in[8]; const float* bg1 = (const float*)d_in[9];
    const float* glw = (const float*)d_in[10]; const float* glb = (const float*)d_in[11];
    const float* Wg2 = (const float*)d_in[12]; const float* bg2 = (const float*)d_in[13];
    const float* Wo = (const float*)d_in[14]; const float* bo = (const float*)d_in[15];
    const float* lw = (const float*)d_in[16]; const float* lb = (const float*)d_in[17];

    float* out   = (float*)d_out;                      // [8192,768]
    float* probs = out + (size_t)MR * Hn;              // [48,2048,2048]

    float* q     = (float*)d_ws;                       // [8192,768]
    float* k     = q + (size_t)MR * Hn;                // [8192,768]
    float* v     = k + (size_t)MR * Hn;                // [8192,768]
    float* g     = v + (size_t)MR * Hn;                // [8192,128]
    float* gates = g + (size_t)MR * WHn;               // [8192,12]
    float* ctx   = k;   // k is dead after scores_kernel
    float* ctxo  = q;   // q is dead after scores_kernel

    dim3 blk(256);
    proj_gemm<<<dim3(Hn / 64, MR / 64), blk, 0, stream>>>(hidden, Wq, bq, q, MR, Hn, Hn);
    proj_gemm<<<dim3(Hn / 64, MR / 64), blk, 0, stream>>>(hidden, Wk, bk, k, MR, Hn, Hn);
    proj_gemm<<<dim3(Hn / 64, MR / 64), blk, 0, stream>>>(hidden, Wv, bv, v, MR, Hn, Hn);
    proj_gemm<<<dim3(WHn / 64, MR / 64), blk, 0, stream>>>(hidden, Wg1, bg1, g, MR, WHn, Hn);
    gate_kernel<<<dim3(MR), dim3(128), 0, stream>>>(g, glw, glb, Wg2, bg2, gates);
    scores_kernel<<<dim3(Sn / 64, Sn / 64, Bn * NHn), blk, 0, stream>>>(q, k, gates, amask, probs);
    softmax_kernel<<<dim3(Bn * NHn * Sn), blk, 0, stream>>>(probs);
    pv_gemm<<<dim3(1, Sn / 64, Bn * NHn), blk, 0, stream>>>(probs, v, ctx);
    proj_gemm<<<dim3(Hn / 64, MR / 64), blk, 0, stream>>>(ctx, Wo, bo, ctxo, MR, Hn, Hn);
    final_ln<<<dim3(MR), blk, 0, stream>>>(ctxo, hidden, lw, lb, out);
}